// Round 12
// baseline (319.442 us; speedup 1.0000x reference)
//
#include <hip/hip_runtime.h>
#include <hip/hip_bf16.h>
#include <cstdint>

#define NN   50000      // nodes
#define NE   800000     // edges (without self loops)
#define NET  850000     // edges + self loops
#define FIN  128
#define FH1  256        // heads*C layer1
#define HD   64
#define NG   64
#define OUTC 10
#define NBS  ((NN + 255) / 256)   // 196 scan blocks

typedef __attribute__((ext_vector_type(8))) short short8v;
typedef __attribute__((ext_vector_type(4))) float f32x4;

__device__ __forceinline__ float bf2f(unsigned short u) {
    union { unsigned int i; float f; } v; v.i = ((unsigned int)u) << 16; return v.f;
}
__device__ __forceinline__ float bflo(unsigned int u) {
    union { unsigned int i; float f; } v; v.i = u << 16; return v.f;
}
__device__ __forceinline__ float bfhi(unsigned int u) {
    union { unsigned int i; float f; } v; v.i = u & 0xFFFF0000u; return v.f;
}
__device__ __forceinline__ unsigned short f2bf(float f) {
    union { float fl; unsigned int i; } v; v.fl = f;
    unsigned int x = v.i;
    return (unsigned short)((x + 0x7FFFu + ((x >> 16) & 1u)) >> 16);
}
__device__ __forceinline__ float leakyr(float v) { return v > 0.f ? v : 0.2f * v; }
__device__ __forceinline__ float elu1(float v)  { return v > 0.f ? v : expm1f(v); }

// ---------------- K1: xp1 = x @ W1 (bf16, HEAD-MAJOR [head][node][64]) + s1,d1 node-major ----------------
// grid ceil(NN/64); block 256 = 4 waves (wave == head); x staged once per block.
__global__ __launch_bounds__(256) void k_gemm1(
    const float* __restrict__ x, const float* __restrict__ W1,
    const float* __restrict__ asrc, const float* __restrict__ adst,
    unsigned short* __restrict__ xp1, float* __restrict__ s1, float* __restrict__ d1)
{
    __shared__ __align__(16) short Ash[64 * 40];    // 64 rows x 32 k (pad 40)
    __shared__ __align__(16) short Bsh[256 * 40];   // 256 n x 32 k (pad 40)
    int row0 = blockIdx.x * 64;
    int tid  = threadIdx.x;
    int wv   = tid >> 6;           // wave == head
    int lane = tid & 63;
    int g    = lane >> 4;          // k-group 0..3
    int c    = lane & 15;

    f32x4 acc[4][4];               // [row-tile][col-tile]
    #pragma unroll
    for (int i = 0; i < 4; i++)
        #pragma unroll
        for (int j = 0; j < 4; j++) acc[i][j] = (f32x4){0.f, 0.f, 0.f, 0.f};

    int sr = tid >> 2;             // staging row 0..63
    int sq = tid & 3;              // staging k-quad

    for (int k0 = 0; k0 < FIN; k0 += 32) {
        {
            int gr = row0 + sr;
            float4 v0 = make_float4(0,0,0,0), v1 = make_float4(0,0,0,0);
            if (gr < NN) {
                const float4* p = reinterpret_cast<const float4*>(x + (size_t)gr * FIN + k0 + sq * 8);
                v0 = p[0]; v1 = p[1];
            }
            short8v pk;
            pk[0] = (short)f2bf(v0.x); pk[1] = (short)f2bf(v0.y);
            pk[2] = (short)f2bf(v0.z); pk[3] = (short)f2bf(v0.w);
            pk[4] = (short)f2bf(v1.x); pk[5] = (short)f2bf(v1.y);
            pk[6] = (short)f2bf(v1.z); pk[7] = (short)f2bf(v1.w);
            *reinterpret_cast<short8v*>(&Ash[sr * 40 + sq * 8]) = pk;
        }
        {
            #pragma unroll
            for (int kg = 0; kg < 4; kg++) {
                short8v pk;
                #pragma unroll
                for (int i = 0; i < 8; i++)
                    pk[i] = (short)f2bf(W1[(size_t)(k0 + kg * 8 + i) * FH1 + tid]);
                *reinterpret_cast<short8v*>(&Bsh[tid * 40 + kg * 8]) = pk;
            }
        }
        __syncthreads();
        short8v bf[4];
        #pragma unroll
        for (int j = 0; j < 4; j++)
            bf[j] = *reinterpret_cast<const short8v*>(&Bsh[(64 * wv + 16 * j + c) * 40 + g * 8]);
        #pragma unroll
        for (int rt = 0; rt < 4; rt++) {
            short8v af = *reinterpret_cast<const short8v*>(&Ash[(16 * rt + c) * 40 + g * 8]);
            #pragma unroll
            for (int j = 0; j < 4; j++)
                acc[rt][j] = __builtin_amdgcn_mfma_f32_16x16x32_bf16(af, bf[j], acc[rt][j], 0, 0, 0);
        }
        __syncthreads();
    }

    float as[4], ad[4];
    #pragma unroll
    for (int j = 0; j < 4; j++) {
        as[j] = asrc[64 * wv + 16 * j + c];
        ad[j] = adst[64 * wv + 16 * j + c];
    }
    #pragma unroll
    for (int rt = 0; rt < 4; rt++) {
        #pragma unroll
        for (int r = 0; r < 4; r++) {
            int row = row0 + 16 * rt + 4 * g + r;
            float sv = 0.f, dv = 0.f;
            #pragma unroll
            for (int j = 0; j < 4; j++) {
                float v = acc[rt][j][r];
                sv = fmaf(v, as[j], sv);
                dv = fmaf(v, ad[j], dv);
                if (row < NN) xp1[((size_t)wv * NN + row) * HD + 16 * j + c] = f2bf(v);
            }
            #pragma unroll
            for (int off = 8; off >= 1; off >>= 1) {
                sv += __shfl_xor(sv, off, 16);
                dv += __shfl_xor(dv, off, 16);
            }
            if (c == 0 && row < NN) {
                s1[row * 4 + wv] = sv;
                d1[row * 4 + wv] = dv;
            }
        }
    }
}

// ---------------- CSR build: histogram of dst ----------------
__global__ __launch_bounds__(256) void k_hist(
    const int* __restrict__ ei, int* __restrict__ deg)
{
    int e = blockIdx.x * 256 + threadIdx.x;
    if (e >= NET) return;
    int dst = (e < NE) ? ei[NE + e] : (e - NE);
    atomicAdd(&deg[dst], 1);
}

// ---------------- hierarchical scan: phase A (block sums) ----------------
__global__ __launch_bounds__(256) void k_scan_a(
    const int* __restrict__ deg, int* __restrict__ part)
{
    __shared__ int sm[256];
    int t = threadIdx.x;
    int idx = blockIdx.x * 256 + t;
    sm[t] = (idx < NN) ? deg[idx] : 0;
    __syncthreads();
    for (int off = 128; off >= 1; off >>= 1) {
        if (t < off) sm[t] += sm[t + off];
        __syncthreads();
    }
    if (t == 0) part[blockIdx.x] = sm[0];
}

// ---------------- phase B: scan the 196 partials (1 block) ----------------
__global__ __launch_bounds__(256) void k_scan_b(
    int* __restrict__ part, int* __restrict__ rowptr)
{
    __shared__ int sm[256];
    int t = threadIdx.x;
    int v = (t < NBS) ? part[t] : 0;
    sm[t] = v;
    __syncthreads();
    for (int off = 1; off < 256; off <<= 1) {
        int u = (t >= off) ? sm[t - off] : 0;
        __syncthreads();
        sm[t] += u;
        __syncthreads();
    }
    if (t < NBS) part[t] = sm[t] - v;   // exclusive prefix of block sums
    if (t == 0) rowptr[NN] = NET;
}

// ---------------- phase C: per-block rescan + offset -> rowptr ----------------
__global__ __launch_bounds__(256) void k_scan_c(
    const int* __restrict__ deg, const int* __restrict__ part,
    int* __restrict__ rowptr)
{
    __shared__ int sm[256];
    int t = threadIdx.x;
    int idx = blockIdx.x * 256 + t;
    int v = (idx < NN) ? deg[idx] : 0;
    sm[t] = v;
    __syncthreads();
    for (int off = 1; off < 256; off <<= 1) {
        int u = (t >= off) ? sm[t - off] : 0;
        __syncthreads();
        sm[t] += u;
        __syncthreads();
    }
    if (idx < NN) rowptr[idx] = part[blockIdx.x] + sm[t] - v;
}

// ---------------- CSR scatter FUSED with layer-1 edge exponentials (head-sliced) ----------------
// es1t[h][p] = exp(leaky(s1[src][h] + d1[dst][h])) in CSR slot order, per head slice.
__global__ __launch_bounds__(256) void k_scatter(
    const int* __restrict__ ei, const int* __restrict__ rowptr,
    int* __restrict__ cursor, int* __restrict__ eidx,
    const float* __restrict__ s1, const float* __restrict__ d1,
    float* __restrict__ es1t)
{
    int e = blockIdx.x * 256 + threadIdx.x;
    if (e >= NET) return;
    int src, dst;
    if (e < NE) { src = ei[e]; dst = ei[NE + e]; }
    else        { src = dst = e - NE; }
    int pos = atomicAdd(&cursor[dst], 1);
    int p = rowptr[dst] + pos;
    eidx[p] = src;
    float4 s = *reinterpret_cast<const float4*>(s1 + (size_t)src * 4);
    float4 d = *reinterpret_cast<const float4*>(d1 + (size_t)dst * 4);
    es1t[0 * NET + p] = __expf(leakyr(s.x + d.x));
    es1t[1 * NET + p] = __expf(leakyr(s.y + d.y));
    es1t[2 * NET + p] = __expf(leakyr(s.z + d.z));
    es1t[3 * NET + p] = __expf(leakyr(s.w + d.w));
}

// ---------------- K3': layer-1 pull — head-split + XCD pin + scalar es/eidx ----------------
// grid NN blocks; head = (b>>1)&3 -> XCDs {2h,2h+1} (b&7 round-robin), so each
// head-wave gathers from its 6.4 MB xp1 slice + 3.4 MB es1t slice only.
// Wave = (node, head); lane = one bf16 column. Inner loop: scalar eidx/es loads,
// saddr-form 128B gathers, 3 VALU/edge/lane (bf2f+fma+den).
__global__ __launch_bounds__(256) void k_pull1(
    const int* __restrict__ rowptr, const int* __restrict__ eidx,
    const float* __restrict__ es1t,
    const unsigned short* __restrict__ xp1, const float* __restrict__ b1,
    unsigned short* __restrict__ h1)
{
    int b = blockIdx.x;
    int head = (b >> 1) & 3;
    int ng = ((b >> 3) << 1) | (b & 1);
    int wv = threadIdx.x >> 6;
    int lane = threadIdx.x & 63;
    int n = ng * 4 + wv;
    if (n >= NN) return;
    const unsigned short* xph = xp1 + (size_t)head * NN * HD;   // uniform base
    const float* esh = es1t + (size_t)head * NET;               // uniform base
    int jb = __builtin_amdgcn_readfirstlane(rowptr[n]);
    int je = __builtin_amdgcn_readfirstlane(rowptr[n + 1]);
    float a = 0.f, den = 0.f;
    int j = jb;
    for (; j + 8 <= je; j += 8) {
        int s[8];
        float es[8];
        #pragma unroll
        for (int q = 0; q < 8; q++) {
            s[q] = eidx[j + q];                 // uniform -> s_load
            es[q] = esh[j + q];                 // uniform -> s_load
        }
        unsigned short xv[8];
        #pragma unroll
        for (int q = 0; q < 8; q++)
            xv[q] = xph[(size_t)s[q] * HD + lane];   // 128B wave gather, saddr-form
        #pragma unroll
        for (int q = 0; q < 8; q++) {
            a = fmaf(bf2f(xv[q]), es[q], a);
            den += es[q];
        }
    }
    for (; j < je; j++) {
        int s = eidx[j];
        float ex = esh[j];
        a = fmaf(bf2f(xph[(size_t)s * HD + lane]), ex, a);
        den += ex;
    }
    float o = elu1(a / den + b1[head * HD + lane]);
    h1[(size_t)n * FH1 + head * HD + lane] = f2bf(o);
}

// ---------------- K5: xp2 = h1 @ W2 (bf16 out, MFMA) + scores s2,d2 ----------------
__global__ __launch_bounds__(256) void k_gemm2(
    const unsigned short* __restrict__ h1, const float* __restrict__ W2,
    const float* __restrict__ asrc2, const float* __restrict__ adst2,
    unsigned short* __restrict__ xp2, float* __restrict__ s2, float* __restrict__ d2)
{
    __shared__ __align__(16) short Ash[64 * 40];
    __shared__ __align__(16) short Bsh[64 * 40];
    int row0 = blockIdx.x * 64;
    int tid  = threadIdx.x;
    int wv   = tid >> 6;
    int lane = tid & 63;
    int g    = lane >> 4;
    int c    = lane & 15;

    f32x4 acc[4] = {{0,0,0,0},{0,0,0,0},{0,0,0,0},{0,0,0,0}};

    int sr = tid >> 2;
    int sq = tid & 3;

    for (int k0 = 0; k0 < FH1; k0 += 32) {
        {
            int gr = row0 + sr;
            uint4 v = make_uint4(0, 0, 0, 0);
            if (gr < NN) v = *reinterpret_cast<const uint4*>(h1 + (size_t)gr * FH1 + k0 + sq * 8);
            *reinterpret_cast<uint4*>(&Ash[sr * 40 + sq * 8]) = v;
        }
        {
            int n  = tid & 63;
            int kg = tid >> 6;
            short8v pk;
            #pragma unroll
            for (int i = 0; i < 8; i++)
                pk[i] = (short)f2bf(W2[(size_t)(k0 + kg * 8 + i) * HD + n]);
            *reinterpret_cast<short8v*>(&Bsh[n * 40 + kg * 8]) = pk;
        }
        __syncthreads();
        short8v af = *reinterpret_cast<const short8v*>(&Ash[(16 * wv + c) * 40 + g * 8]);
        #pragma unroll
        for (int j = 0; j < 4; j++) {
            short8v bf = *reinterpret_cast<const short8v*>(&Bsh[(16 * j + c) * 40 + g * 8]);
            acc[j] = __builtin_amdgcn_mfma_f32_16x16x32_bf16(af, bf, acc[j], 0, 0, 0);
        }
        __syncthreads();
    }

    float as[4], ad[4];
    #pragma unroll
    for (int j = 0; j < 4; j++) {
        as[j] = asrc2[16 * j + c];
        ad[j] = adst2[16 * j + c];
    }
    #pragma unroll
    for (int r = 0; r < 4; r++) {
        int row = row0 + 16 * wv + 4 * g + r;
        float sv = 0.f, dv = 0.f;
        #pragma unroll
        for (int j = 0; j < 4; j++) {
            float v = acc[j][r];
            sv = fmaf(v, as[j], sv);
            dv = fmaf(v, ad[j], dv);
            if (row < NN) xp2[(size_t)row * HD + 16 * j + c] = f2bf(v);
        }
        #pragma unroll
        for (int off = 8; off >= 1; off >>= 1) {
            sv += __shfl_xor(sv, off, 16);
            dv += __shfl_xor(dv, off, 16);
        }
        if (c == 0 && row < NN) { s2[row] = sv; d2[row] = dv; }
    }
}

// ---------------- K7': layer-2 pull — 2 edges per wave, inline exp (round-7 form) ----------------
__global__ __launch_bounds__(256) void k_pull2(
    const int* __restrict__ rowptr, const int* __restrict__ eidx,
    const float* __restrict__ s2, const float* __restrict__ d2,
    const unsigned short* __restrict__ xp2, const float* __restrict__ b2,
    float* __restrict__ h2)
{
    int wv = threadIdx.x >> 6;
    int lane = threadIdx.x & 63;
    int n = blockIdx.x * 4 + wv;
    if (n >= NN) return;
    int half = lane >> 5;          // which edge of the pair
    int c = lane & 31;             // 2 cols per lane: 2c, 2c+1
    float dv = d2[n];
    int jb = __builtin_amdgcn_readfirstlane(rowptr[n]);
    int je = __builtin_amdgcn_readfirstlane(rowptr[n + 1]);
    float a0 = 0.f, a1 = 0.f, den = 0.f;
    int j = jb;
    for (; j + 16 <= je; j += 16) {
        #pragma unroll
        for (int p = 0; p < 8; p++) {
            int e = j + 2 * p + half;
            int src = eidx[e];
            float sc = s2[src];
            unsigned int u = *reinterpret_cast<const unsigned int*>(xp2 + (size_t)src * HD + 2 * c);
            float ex = __expf(leakyr(sc + dv));
            a0 = fmaf(bflo(u), ex, a0);
            a1 = fmaf(bfhi(u), ex, a1);
            den += ex;
        }
    }
    for (; j < je; j += 2) {
        int e = j + half;
        bool valid = e < je;
        int ec = valid ? e : (je - 1);
        int src = eidx[ec];
        float sc = s2[src];
        unsigned int u = *reinterpret_cast<const unsigned int*>(xp2 + (size_t)src * HD + 2 * c);
        float ex = valid ? __expf(leakyr(sc + dv)) : 0.f;
        a0 = fmaf(bflo(u), ex, a0);
        a1 = fmaf(bfhi(u), ex, a1);
        den += ex;
    }
    a0 += __shfl_xor(a0, 32);
    a1 += __shfl_xor(a1, 32);
    den += __shfl_xor(den, 32);
    if (half == 0) {
        float inv = 1.0f / den;
        float2 bb = *reinterpret_cast<const float2*>(b2 + 2 * c);
        float2 o;
        o.x = elu1(fmaf(a0, inv, bb.x));
        o.y = elu1(fmaf(a1, inv, bb.y));
        *reinterpret_cast<float2*>(h2 + (size_t)n * HD + 2 * c) = o;
    }
}

// ---------------- K8: per-graph partial sums (grid NG x 8, atomic combine) ----------------
__global__ __launch_bounds__(256) void k_pool(
    const float* __restrict__ h2, const int* __restrict__ batch,
    float* __restrict__ pooled /* SUMS, pre-zeroed */)
{
    int g = blockIdx.x;
    int sslice = blockIdx.y;
    int lo = 0, hi = NN;
    while (lo < hi) { int m = (lo + hi) >> 1; if (batch[m] < g) lo = m + 1; else hi = m; }
    int start = lo;
    hi = NN;
    while (lo < hi) { int m = (lo + hi) >> 1; if (batch[m] < g + 1) lo = m + 1; else hi = m; }
    int end = lo;
    int len = end - start;
    int chunk = (len + 7) >> 3;
    int b0 = start + sslice * chunk;
    int b1 = min(b0 + chunk, end);
    int c = threadIdx.x & 63;
    int rg = threadIdx.x >> 6;
    float sum = 0.f;
    for (int n = b0 + rg; n < b1; n += 4)
        sum += h2[(size_t)n * HD + c];
    __shared__ float red[4][64];
    red[rg][c] = sum;
    __syncthreads();
    if (threadIdx.x < 64) {
        float tot = red[0][c] + red[1][c] + red[2][c] + red[3][c];
        if (tot != 0.f) atomicAdd(&pooled[g * HD + c], tot);
    }
}

// ---------------- K9: final linear (pooled are SUMS; divide by count) ----------------
__global__ __launch_bounds__(256) void k_final(
    const float* __restrict__ pooled, const int* __restrict__ batch,
    const float* __restrict__ Wl, const float* __restrict__ bl,
    float* __restrict__ out)
{
    int t = blockIdx.x * 256 + threadIdx.x;
    if (t >= NG * OUTC) return;
    int g = t / OUTC, o = t % OUTC;
    int lo = 0, hi = NN;
    while (lo < hi) { int m = (lo + hi) >> 1; if (batch[m] < g) lo = m + 1; else hi = m; }
    int start = lo;
    hi = NN;
    while (lo < hi) { int m = (lo + hi) >> 1; if (batch[m] < g + 1) lo = m + 1; else hi = m; }
    float cnt = (float)(lo - start);
    float acc = 0.f;
    #pragma unroll
    for (int k = 0; k < HD; k++)
        acc = fmaf(pooled[g * HD + k], Wl[k * OUTC + o], acc);
    out[t] = acc / fmaxf(cnt, 1.f) + bl[o];
}

extern "C" void kernel_launch(void* const* d_in, const int* in_sizes, int n_in,
                              void* d_out, int out_size, void* d_ws, size_t ws_size,
                              hipStream_t stream) {
    const float* x     = (const float*)d_in[0];
    const int*   ei    = (const int*)d_in[1];
    const int*   batch = (const int*)d_in[2];
    const float* W1    = (const float*)d_in[3];
    const float* as1   = (const float*)d_in[4];
    const float* ad1   = (const float*)d_in[5];
    const float* b1    = (const float*)d_in[6];
    const float* W2    = (const float*)d_in[7];
    const float* as2   = (const float*)d_in[8];
    const float* ad2   = (const float*)d_in[9];
    const float* b2    = (const float*)d_in[10];
    const float* Wl    = (const float*)d_in[11];
    const float* bl    = (const float*)d_in[12];
    float* out = (float*)d_out;

    char* w = (char*)d_ws;
    size_t off = 0;
    auto alloc = [&](size_t bytes) {
        void* p = (void*)(w + off);
        off = (off + bytes + 255) & ~(size_t)255;
        return p;
    };
    // zero-initialized block first (deg + cursor + pooled sums)
    int* deg    = (int*)alloc((size_t)NN * 4);
    int* cursor = (int*)alloc((size_t)NN * 4);
    float* pooled = (float*)alloc((size_t)NG * HD * 4);
    size_t zbytes = off;
    int* part   = (int*)alloc((size_t)NBS * 4);
    int* rowptr = (int*)alloc((size_t)(NN + 1) * 4);
    int* eidx   = (int*)alloc((size_t)NET * 4);
    float* es1t = (float*)alloc((size_t)NET * 4 * 4);   // [head][edge]
    unsigned short* xp1 = (unsigned short*)alloc((size_t)NN * FH1 * 2);  // [head][node][64]
    unsigned short* h1  = (unsigned short*)alloc((size_t)NN * FH1 * 2);  // [node][256]
    float* s1  = (float*)alloc((size_t)NN * 4 * 4);
    float* d1s = (float*)alloc((size_t)NN * 4 * 4);
    unsigned short* xp2 = (unsigned short*)alloc((size_t)NN * HD * 2);
    float* s2  = (float*)alloc((size_t)NN * 4);
    float* d2s = (float*)alloc((size_t)NN * 4);
    float* h2  = (float*)alloc((size_t)NN * HD * 4);

    hipMemsetAsync(d_ws, 0, zbytes, stream);

    // gemm1 first (scatter needs its scores)
    k_gemm1<<<(NN + 63) / 64, 256, 0, stream>>>(x, W1, as1, ad1, xp1, s1, d1s);
    // CSR build + fused layer-1 edge exponentials
    k_hist   <<<(NET + 255) / 256, 256, 0, stream>>>(ei, deg);
    k_scan_a <<<NBS, 256, 0, stream>>>(deg, part);
    k_scan_b <<<1, 256, 0, stream>>>(part, rowptr);
    k_scan_c <<<NBS, 256, 0, stream>>>(deg, part, rowptr);
    k_scatter<<<(NET + 255) / 256, 256, 0, stream>>>(ei, rowptr, cursor, eidx, s1, d1s, es1t);

    k_pull1<<<NN, 256, 0, stream>>>(rowptr, eidx, es1t, xp1, b1, h1);
    k_gemm2<<<(NN + 63) / 64, 256, 0, stream>>>(h1, W2, as2, ad2, xp2, s2, d2s);
    k_pull2<<<(NN + 3) / 4, 256, 0, stream>>>(rowptr, eidx, s2, d2s, xp2, b2, h2);
    dim3 gp(NG, 8);
    k_pool <<<gp, 256, 0, stream>>>(h2, batch, pooled);
    k_final<<<(NG * OUTC + 255) / 256, 256, 0, stream>>>(pooled, batch, Wl, bl, out);
}

// Round 13
// 256.890 us; speedup vs baseline: 1.2435x; 1.2435x over previous
//
#include <hip/hip_runtime.h>
#include <hip/hip_bf16.h>
#include <cstdint>

#define NN   50000      // nodes
#define NE   800000     // edges (without self loops)
#define NET  850000     // edges + self loops
#define FIN  128
#define FH1  256        // heads*C layer1
#define HD   64
#define NG   64
#define OUTC 10
#define NBS  ((NN + 255) / 256)   // 196 scan blocks

typedef __attribute__((ext_vector_type(8))) short short8v;
typedef __attribute__((ext_vector_type(4))) float f32x4;

__device__ __forceinline__ float bf2f(unsigned short u) {
    union { unsigned int i; float f; } v; v.i = ((unsigned int)u) << 16; return v.f;
}
__device__ __forceinline__ float bflo(unsigned int u) {
    union { unsigned int i; float f; } v; v.i = u << 16; return v.f;
}
__device__ __forceinline__ float bfhi(unsigned int u) {
    union { unsigned int i; float f; } v; v.i = u & 0xFFFF0000u; return v.f;
}
__device__ __forceinline__ unsigned short f2bf(float f) {
    union { float fl; unsigned int i; } v; v.fl = f;
    unsigned int x = v.i;
    return (unsigned short)((x + 0x7FFFu + ((x >> 16) & 1u)) >> 16);
}
__device__ __forceinline__ float leakyr(float v) { return v > 0.f ? v : 0.2f * v; }
__device__ __forceinline__ float elu1(float v)  { return v > 0.f ? v : expm1f(v); }

// ---------------- K1: xp1 = x @ W1 (bf16 out, MFMA) + scores s1t, d1 ----------------
// grid ceil(NN/64); block 256 = 4 waves; block tile 64x256 (x staged ONCE);
// wave wv = head wv, covering cols [64wv, 64wv+64), all 64 rows (4 row-tiles).
__global__ __launch_bounds__(256) void k_gemm1(
    const float* __restrict__ x, const float* __restrict__ W1,
    const float* __restrict__ asrc, const float* __restrict__ adst,
    unsigned short* __restrict__ xp1, float* __restrict__ s1t, float* __restrict__ d1)
{
    __shared__ __align__(16) short Ash[64 * 40];    // 64 rows x 32 k (pad 40)
    __shared__ __align__(16) short Bsh[256 * 40];   // 256 n x 32 k (pad 40)
    int row0 = blockIdx.x * 64;
    int tid  = threadIdx.x;
    int wv   = tid >> 6;           // wave == head
    int lane = tid & 63;
    int g    = lane >> 4;          // k-group 0..3
    int c    = lane & 15;

    f32x4 acc[4][4];               // [row-tile][col-tile]
    #pragma unroll
    for (int i = 0; i < 4; i++)
        #pragma unroll
        for (int j = 0; j < 4; j++) acc[i][j] = (f32x4){0.f, 0.f, 0.f, 0.f};

    int sr = tid >> 2;             // staging row 0..63
    int sq = tid & 3;              // staging k-quad

    for (int k0 = 0; k0 < FIN; k0 += 32) {
        // stage A: x[row0..+64][k0..+32] -> bf16 (once per block)
        {
            int gr = row0 + sr;
            float4 v0 = make_float4(0,0,0,0), v1 = make_float4(0,0,0,0);
            if (gr < NN) {
                const float4* p = reinterpret_cast<const float4*>(x + (size_t)gr * FIN + k0 + sq * 8);
                v0 = p[0]; v1 = p[1];
            }
            short8v pk;
            pk[0] = (short)f2bf(v0.x); pk[1] = (short)f2bf(v0.y);
            pk[2] = (short)f2bf(v0.z); pk[3] = (short)f2bf(v0.w);
            pk[4] = (short)f2bf(v1.x); pk[5] = (short)f2bf(v1.y);
            pk[6] = (short)f2bf(v1.z); pk[7] = (short)f2bf(v1.w);
            *reinterpret_cast<short8v*>(&Ash[sr * 40 + sq * 8]) = pk;
        }
        // stage B transposed: W1[k0..+32][0..256) -> Bsh[n][k]; thread owns n=tid
        {
            #pragma unroll
            for (int kg = 0; kg < 4; kg++) {
                short8v pk;
                #pragma unroll
                for (int i = 0; i < 8; i++)
                    pk[i] = (short)f2bf(W1[(size_t)(k0 + kg * 8 + i) * FH1 + tid]);
                *reinterpret_cast<short8v*>(&Bsh[tid * 40 + kg * 8]) = pk;
            }
        }
        __syncthreads();
        short8v bf[4];
        #pragma unroll
        for (int j = 0; j < 4; j++)
            bf[j] = *reinterpret_cast<const short8v*>(&Bsh[(64 * wv + 16 * j + c) * 40 + g * 8]);
        #pragma unroll
        for (int rt = 0; rt < 4; rt++) {
            short8v af = *reinterpret_cast<const short8v*>(&Ash[(16 * rt + c) * 40 + g * 8]);
            #pragma unroll
            for (int j = 0; j < 4; j++)
                acc[rt][j] = __builtin_amdgcn_mfma_f32_16x16x32_bf16(af, bf[j], acc[rt][j], 0, 0, 0);
        }
        __syncthreads();
    }

    int n0 = 64 * wv;
    float as[4], ad[4];
    #pragma unroll
    for (int j = 0; j < 4; j++) {
        as[j] = asrc[n0 + 16 * j + c];
        ad[j] = adst[n0 + 16 * j + c];
    }
    #pragma unroll
    for (int rt = 0; rt < 4; rt++) {
        #pragma unroll
        for (int r = 0; r < 4; r++) {
            int row = row0 + 16 * rt + 4 * g + r;
            float sv = 0.f, dv = 0.f;
            #pragma unroll
            for (int j = 0; j < 4; j++) {
                float v = acc[rt][j][r];
                sv = fmaf(v, as[j], sv);
                dv = fmaf(v, ad[j], dv);
                if (row < NN) xp1[(size_t)row * FH1 + n0 + 16 * j + c] = f2bf(v);
            }
            #pragma unroll
            for (int off = 8; off >= 1; off >>= 1) {
                sv += __shfl_xor(sv, off, 16);
                dv += __shfl_xor(dv, off, 16);
            }
            if (c == 0 && row < NN) {
                s1t[(size_t)wv * NN + row] = sv;
                d1[row * 4 + wv] = dv;
            }
        }
    }
}

// ---------------- CSR build: histogram of dst ----------------
__global__ __launch_bounds__(256) void k_hist(
    const int* __restrict__ ei, int* __restrict__ deg)
{
    int e = blockIdx.x * 256 + threadIdx.x;
    if (e >= NET) return;
    int dst = (e < NE) ? ei[NE + e] : (e - NE);
    atomicAdd(&deg[dst], 1);
}

// ---------------- hierarchical scan: phase A (block sums) ----------------
__global__ __launch_bounds__(256) void k_scan_a(
    const int* __restrict__ deg, int* __restrict__ part)
{
    __shared__ int sm[256];
    int t = threadIdx.x;
    int idx = blockIdx.x * 256 + t;
    sm[t] = (idx < NN) ? deg[idx] : 0;
    __syncthreads();
    for (int off = 128; off >= 1; off >>= 1) {
        if (t < off) sm[t] += sm[t + off];
        __syncthreads();
    }
    if (t == 0) part[blockIdx.x] = sm[0];
}

// ---------------- phase B: scan the 196 partials (1 block) ----------------
__global__ __launch_bounds__(256) void k_scan_b(
    int* __restrict__ part, int* __restrict__ rowptr)
{
    __shared__ int sm[256];
    int t = threadIdx.x;
    int v = (t < NBS) ? part[t] : 0;
    sm[t] = v;
    __syncthreads();
    for (int off = 1; off < 256; off <<= 1) {
        int u = (t >= off) ? sm[t - off] : 0;
        __syncthreads();
        sm[t] += u;
        __syncthreads();
    }
    if (t < NBS) part[t] = sm[t] - v;   // exclusive prefix of block sums
    if (t == 0) rowptr[NN] = NET;
}

// ---------------- phase C: per-block rescan + offset -> rowptr ----------------
__global__ __launch_bounds__(256) void k_scan_c(
    const int* __restrict__ deg, const int* __restrict__ part,
    int* __restrict__ rowptr)
{
    __shared__ int sm[256];
    int t = threadIdx.x;
    int idx = blockIdx.x * 256 + t;
    int v = (idx < NN) ? deg[idx] : 0;
    sm[t] = v;
    __syncthreads();
    for (int off = 1; off < 256; off <<= 1) {
        int u = (t >= off) ? sm[t - off] : 0;
        __syncthreads();
        sm[t] += u;
        __syncthreads();
    }
    if (idx < NN) rowptr[idx] = part[blockIdx.x] + sm[t] - v;
}

// ---------------- CSR build: scatter edge srcs into slots ----------------
__global__ __launch_bounds__(256) void k_scatter(
    const int* __restrict__ ei, const int* __restrict__ rowptr,
    int* __restrict__ cursor, int* __restrict__ eidx)
{
    int e = blockIdx.x * 256 + threadIdx.x;
    if (e >= NET) return;
    int src, dst;
    if (e < NE) { src = ei[e]; dst = ei[NE + e]; }
    else        { src = dst = e - NE; }
    int pos = atomicAdd(&cursor[dst], 1);
    eidx[rowptr[dst] + pos] = src;
}

// ---------------- K3': layer-1 pull — scalar-pipe addressing, 8-way MLP ----------------
// wave per node; lane: head = lane>>4, cols c0 = lane*4 (4 of 256). 512B gather/edge.
__global__ __launch_bounds__(256) void k_pull1(
    const int* __restrict__ rowptr, const int* __restrict__ eidx,
    const float* __restrict__ s1t, const float* __restrict__ d1,
    const unsigned short* __restrict__ xp1, const float* __restrict__ b1,
    unsigned short* __restrict__ h1)
{
    int wv = threadIdx.x >> 6;
    int lane = threadIdx.x & 63;
    int n = blockIdx.x * 4 + wv;
    if (n >= NN) return;
    int head = lane >> 4;                  // 16 lanes per head
    int c0 = lane * 4;                     // 4 consecutive cols per lane
    int hNN = head * NN;                   // per-lane, loop-invariant score offset
    float dv = d1[(size_t)n * 4 + head];
    int jb = __builtin_amdgcn_readfirstlane(rowptr[n]);
    int je = __builtin_amdgcn_readfirstlane(rowptr[n + 1]);
    float a0 = 0.f, a1 = 0.f, a2 = 0.f, a3 = 0.f;
    float den = 0.f;
    int j = jb;
    for (; j + 8 <= je; j += 8) {
        int s[8];
        #pragma unroll
        for (int q = 0; q < 8; q++) s[q] = eidx[j + q];       // uniform -> s_load
        float sc[8];
        uint2 u[8];
        #pragma unroll
        for (int q = 0; q < 8; q++) {
            const float* srow = s1t + s[q];
            sc[q] = srow[hNN];
            const unsigned short* xrow = xp1 + (size_t)s[q] * FH1;
            u[q] = *reinterpret_cast<const uint2*>(xrow + c0);
        }
        #pragma unroll
        for (int q = 0; q < 8; q++) {
            float ex = __expf(leakyr(sc[q] + dv));
            a0 = fmaf(bflo(u[q].x), ex, a0);
            a1 = fmaf(bfhi(u[q].x), ex, a1);
            a2 = fmaf(bflo(u[q].y), ex, a2);
            a3 = fmaf(bfhi(u[q].y), ex, a3);
            den += ex;
        }
    }
    for (; j < je; j++) {
        int src = eidx[j];
        const float* srow = s1t + src;
        float ex = __expf(leakyr(srow[hNN] + dv));
        const unsigned short* xrow = xp1 + (size_t)src * FH1;
        uint2 u = *reinterpret_cast<const uint2*>(xrow + c0);
        a0 = fmaf(bflo(u.x), ex, a0);
        a1 = fmaf(bfhi(u.x), ex, a1);
        a2 = fmaf(bflo(u.y), ex, a2);
        a3 = fmaf(bfhi(u.y), ex, a3);
        den += ex;
    }
    float inv = 1.0f / den;
    float4 b = *reinterpret_cast<const float4*>(b1 + c0);
    ushort4 st;
    st.x = f2bf(elu1(fmaf(a0, inv, b.x)));
    st.y = f2bf(elu1(fmaf(a1, inv, b.y)));
    st.z = f2bf(elu1(fmaf(a2, inv, b.z)));
    st.w = f2bf(elu1(fmaf(a3, inv, b.w)));
    *reinterpret_cast<ushort4*>(h1 + (size_t)n * FH1 + c0) = st;
}

// ---------------- K5: xp2 = h1 @ W2 (bf16 out, MFMA) + scores s2,d2 ----------------
// grid ceil(NN/64); block 256 = 4 waves; 64x64 tile, BK=32, K=256.
__global__ __launch_bounds__(256) void k_gemm2(
    const unsigned short* __restrict__ h1, const float* __restrict__ W2,
    const float* __restrict__ asrc2, const float* __restrict__ adst2,
    unsigned short* __restrict__ xp2, float* __restrict__ s2, float* __restrict__ d2)
{
    __shared__ __align__(16) short Ash[64 * 40];
    __shared__ __align__(16) short Bsh[64 * 40];
    int row0 = blockIdx.x * 64;
    int tid  = threadIdx.x;
    int wv   = tid >> 6;
    int lane = tid & 63;
    int g    = lane >> 4;
    int c    = lane & 15;

    f32x4 acc[4] = {{0,0,0,0},{0,0,0,0},{0,0,0,0},{0,0,0,0}};

    int sr = tid >> 2;
    int sq = tid & 3;

    for (int k0 = 0; k0 < FH1; k0 += 32) {
        {
            int gr = row0 + sr;
            uint4 v = make_uint4(0, 0, 0, 0);
            if (gr < NN) v = *reinterpret_cast<const uint4*>(h1 + (size_t)gr * FH1 + k0 + sq * 8);
            *reinterpret_cast<uint4*>(&Ash[sr * 40 + sq * 8]) = v;
        }
        {
            int n  = tid & 63;
            int kg = tid >> 6;
            short8v pk;
            #pragma unroll
            for (int i = 0; i < 8; i++)
                pk[i] = (short)f2bf(W2[(size_t)(k0 + kg * 8 + i) * HD + n]);
            *reinterpret_cast<short8v*>(&Bsh[n * 40 + kg * 8]) = pk;
        }
        __syncthreads();
        short8v af = *reinterpret_cast<const short8v*>(&Ash[(16 * wv + c) * 40 + g * 8]);
        #pragma unroll
        for (int j = 0; j < 4; j++) {
            short8v bf = *reinterpret_cast<const short8v*>(&Bsh[(16 * j + c) * 40 + g * 8]);
            acc[j] = __builtin_amdgcn_mfma_f32_16x16x32_bf16(af, bf, acc[j], 0, 0, 0);
        }
        __syncthreads();
    }

    float as[4], ad[4];
    #pragma unroll
    for (int j = 0; j < 4; j++) {
        as[j] = asrc2[16 * j + c];
        ad[j] = adst2[16 * j + c];
    }
    #pragma unroll
    for (int r = 0; r < 4; r++) {
        int row = row0 + 16 * wv + 4 * g + r;
        float sv = 0.f, dv = 0.f;
        #pragma unroll
        for (int j = 0; j < 4; j++) {
            float v = acc[j][r];
            sv = fmaf(v, as[j], sv);
            dv = fmaf(v, ad[j], dv);
            if (row < NN) xp2[(size_t)row * HD + 16 * j + c] = f2bf(v);
        }
        #pragma unroll
        for (int off = 8; off >= 1; off >>= 1) {
            sv += __shfl_xor(sv, off, 16);
            dv += __shfl_xor(dv, off, 16);
        }
        if (c == 0 && row < NN) { s2[row] = sv; d2[row] = dv; }
    }
}

// ---------------- K7': layer-2 pull — 2 edges per wave (half-wave each) ----------------
__global__ __launch_bounds__(256) void k_pull2(
    const int* __restrict__ rowptr, const int* __restrict__ eidx,
    const float* __restrict__ s2, const float* __restrict__ d2,
    const unsigned short* __restrict__ xp2, const float* __restrict__ b2,
    float* __restrict__ h2)
{
    int wv = threadIdx.x >> 6;
    int lane = threadIdx.x & 63;
    int n = blockIdx.x * 4 + wv;
    if (n >= NN) return;
    int half = lane >> 5;          // which edge of the pair
    int c = lane & 31;             // 2 cols per lane: 2c, 2c+1
    float dv = d2[n];
    int jb = __builtin_amdgcn_readfirstlane(rowptr[n]);
    int je = __builtin_amdgcn_readfirstlane(rowptr[n + 1]);
    float a0 = 0.f, a1 = 0.f, den = 0.f;
    int j = jb;
    for (; j + 16 <= je; j += 16) {
        #pragma unroll
        for (int p = 0; p < 8; p++) {
            int e = j + 2 * p + half;
            int src = eidx[e];
            float sc = s2[src];
            unsigned int u = *reinterpret_cast<const unsigned int*>(xp2 + (size_t)src * HD + 2 * c);
            float ex = __expf(leakyr(sc + dv));
            a0 = fmaf(bflo(u), ex, a0);
            a1 = fmaf(bfhi(u), ex, a1);
            den += ex;
        }
    }
    for (; j < je; j += 2) {
        int e = j + half;
        bool valid = e < je;
        int ec = valid ? e : (je - 1);
        int src = eidx[ec];
        float sc = s2[src];
        unsigned int u = *reinterpret_cast<const unsigned int*>(xp2 + (size_t)src * HD + 2 * c);
        float ex = valid ? __expf(leakyr(sc + dv)) : 0.f;
        a0 = fmaf(bflo(u), ex, a0);
        a1 = fmaf(bfhi(u), ex, a1);
        den += ex;
    }
    a0 += __shfl_xor(a0, 32);
    a1 += __shfl_xor(a1, 32);
    den += __shfl_xor(den, 32);
    if (half == 0) {
        float inv = 1.0f / den;
        float2 bb = *reinterpret_cast<const float2*>(b2 + 2 * c);
        float2 o;
        o.x = elu1(fmaf(a0, inv, bb.x));
        o.y = elu1(fmaf(a1, inv, bb.y));
        *reinterpret_cast<float2*>(h2 + (size_t)n * HD + 2 * c) = o;
    }
}

// ---------------- K8: per-graph partial sums (grid NG x 8, atomic combine) ----------------
__global__ __launch_bounds__(256) void k_pool(
    const float* __restrict__ h2, const int* __restrict__ batch,
    float* __restrict__ pooled /* SUMS, pre-zeroed */)
{
    int g = blockIdx.x;
    int sslice = blockIdx.y;
    int lo = 0, hi = NN;
    while (lo < hi) { int m = (lo + hi) >> 1; if (batch[m] < g) lo = m + 1; else hi = m; }
    int start = lo;
    hi = NN;
    while (lo < hi) { int m = (lo + hi) >> 1; if (batch[m] < g + 1) lo = m + 1; else hi = m; }
    int end = lo;
    int len = end - start;
    int chunk = (len + 7) >> 3;
    int b0 = start + sslice * chunk;
    int b1 = min(b0 + chunk, end);
    int c = threadIdx.x & 63;
    int rg = threadIdx.x >> 6;
    float sum = 0.f;
    for (int n = b0 + rg; n < b1; n += 4)
        sum += h2[(size_t)n * HD + c];
    __shared__ float red[4][64];
    red[rg][c] = sum;
    __syncthreads();
    if (threadIdx.x < 64) {
        float tot = red[0][c] + red[1][c] + red[2][c] + red[3][c];
        if (tot != 0.f) atomicAdd(&pooled[g * HD + c], tot);
    }
}

// ---------------- K9: final linear (pooled are SUMS; divide by count) ----------------
__global__ __launch_bounds__(256) void k_final(
    const float* __restrict__ pooled, const int* __restrict__ batch,
    const float* __restrict__ Wl, const float* __restrict__ bl,
    float* __restrict__ out)
{
    int t = blockIdx.x * 256 + threadIdx.x;
    if (t >= NG * OUTC) return;
    int g = t / OUTC, o = t % OUTC;
    int lo = 0, hi = NN;
    while (lo < hi) { int m = (lo + hi) >> 1; if (batch[m] < g) lo = m + 1; else hi = m; }
    int start = lo;
    hi = NN;
    while (lo < hi) { int m = (lo + hi) >> 1; if (batch[m] < g + 1) lo = m + 1; else hi = m; }
    float cnt = (float)(lo - start);
    float acc = 0.f;
    #pragma unroll
    for (int k = 0; k < HD; k++)
        acc = fmaf(pooled[g * HD + k], Wl[k * OUTC + o], acc);
    out[t] = acc / fmaxf(cnt, 1.f) + bl[o];
}

extern "C" void kernel_launch(void* const* d_in, const int* in_sizes, int n_in,
                              void* d_out, int out_size, void* d_ws, size_t ws_size,
                              hipStream_t stream) {
    const float* x     = (const float*)d_in[0];
    const int*   ei    = (const int*)d_in[1];
    const int*   batch = (const int*)d_in[2];
    const float* W1    = (const float*)d_in[3];
    const float* as1   = (const float*)d_in[4];
    const float* ad1   = (const float*)d_in[5];
    const float* b1    = (const float*)d_in[6];
    const float* W2    = (const float*)d_in[7];
    const float* as2   = (const float*)d_in[8];
    const float* ad2   = (const float*)d_in[9];
    const float* b2    = (const float*)d_in[10];
    const float* Wl    = (const float*)d_in[11];
    const float* bl    = (const float*)d_in[12];
    float* out = (float*)d_out;

    char* w = (char*)d_ws;
    size_t off = 0;
    auto alloc = [&](size_t bytes) {
        void* p = (void*)(w + off);
        off = (off + bytes + 255) & ~(size_t)255;
        return p;
    };
    // zero-initialized block first (deg + cursor + pooled sums)
    int* deg    = (int*)alloc((size_t)NN * 4);
    int* cursor = (int*)alloc((size_t)NN * 4);
    float* pooled = (float*)alloc((size_t)NG * HD * 4);
    size_t zbytes = off;
    int* part   = (int*)alloc((size_t)NBS * 4);
    int* rowptr = (int*)alloc((size_t)(NN + 1) * 4);
    int* eidx   = (int*)alloc((size_t)NET * 4);
    unsigned short* xp1 = (unsigned short*)alloc((size_t)NN * FH1 * 2);
    unsigned short* h1  = (unsigned short*)alloc((size_t)NN * FH1 * 2);
    float* s1t = (float*)alloc((size_t)NN * 4 * 4);
    float* d1s = (float*)alloc((size_t)NN * 4 * 4);
    unsigned short* xp2 = (unsigned short*)alloc((size_t)NN * HD * 2);
    float* s2  = (float*)alloc((size_t)NN * 4);
    float* d2s = (float*)alloc((size_t)NN * 4);
    float* h2  = (float*)alloc((size_t)NN * HD * 4);

    hipMemsetAsync(d_ws, 0, zbytes, stream);

    // CSR build
    k_hist   <<<(NET + 255) / 256, 256, 0, stream>>>(ei, deg);
    k_scan_a <<<NBS, 256, 0, stream>>>(deg, part);
    k_scan_b <<<1, 256, 0, stream>>>(part, rowptr);
    k_scan_c <<<NBS, 256, 0, stream>>>(deg, part, rowptr);
    k_scatter<<<(NET + 255) / 256, 256, 0, stream>>>(ei, rowptr, cursor, eidx);

    k_gemm1<<<(NN + 63) / 64, 256, 0, stream>>>(x, W1, as1, ad1, xp1, s1t, d1s);
    k_pull1<<<(NN + 3) / 4, 256, 0, stream>>>(rowptr, eidx, s1t, d1s, xp1, b1, h1);
    k_gemm2<<<(NN + 63) / 64, 256, 0, stream>>>(h1, W2, as2, ad2, xp2, s2, d2s);
    k_pull2<<<(NN + 3) / 4, 256, 0, stream>>>(rowptr, eidx, s2, d2s, xp2, b2, h2);
    dim3 gp(NG, 8);
    k_pool <<<gp, 256, 0, stream>>>(h2, batch, pooled);
    k_final<<<(NG * OUTC + 255) / 256, 256, 0, stream>>>(pooled, batch, Wl, bl, out);
}